// Round 1
// baseline (786.625 us; speedup 1.0000x reference)
//
#include <hip/hip_runtime.h>
#include <hip/hip_bf16.h>

#define NPTS 50000
#define CIN  512
#define PCH  128
#define KNB  27
#define EPSV 1e-5f
#define NEGS 0.1f

typedef __bf16 bf16;
typedef __bf16 bf16x8 __attribute__((ext_vector_type(8)));
typedef __bf16 bf16x4 __attribute__((ext_vector_type(4)));
typedef float  f32x4  __attribute__((ext_vector_type(4)));

// ---------------- weight transpose + bf16 convert: dst[C][R] = src[R][C] ----
__global__ void tcvt_kernel(const float* __restrict__ src, bf16* __restrict__ dst,
                            int R, int Ccols) {
  int i = blockIdx.x * blockDim.x + threadIdx.x;
  if (i >= R * Ccols) return;
  int c = i / R, r = i - c * R;
  dst[i] = (bf16)src[(size_t)r * Ccols + c];
}

// ---------------- valid = mask > 0 ----------------
__global__ void valid_kernel(const float* __restrict__ mask, float* __restrict__ valid) {
  int n = blockIdx.x * blockDim.x + threadIdx.x;
  if (n >= NPTS) return;
  valid[n] = mask[n] > 0.f ? 1.f : 0.f;
}

// ---------------- nbrT[k][n] = nbr[n][k] ----------------
__global__ void nbrT_kernel(const int* __restrict__ nbr, int* __restrict__ nbrT) {
  int i = blockIdx.x * blockDim.x + threadIdx.x;
  if (i >= KNB * NPTS) return;
  int k = i / NPTS, n = i - k * NPTS;
  nbrT[i] = nbr[n * KNB + k];
}

// ---------------- coverage: ratio + valid2 ----------------
__global__ void msum_kernel(const int* __restrict__ nbr, const float* __restrict__ valid,
                            float* __restrict__ ratio, float* __restrict__ valid2) {
  int n = blockIdx.x * blockDim.x + threadIdx.x;
  if (n >= NPTS) return;
  float s = 0.f;
#pragma unroll
  for (int k = 0; k < KNB; ++k) s += valid[nbr[n * KNB + k]];
  ratio[n]  = s > 0.f ? 27.0f / s : 0.f;
  valid2[n] = s > 0.f ? 1.f : 0.f;
}

// ---------------- channel stats (blockDim.x == C) ----------------
__global__ void stats_kernel(const float* __restrict__ buf, float* __restrict__ ssum,
                             float* __restrict__ ssq) {
  int C = blockDim.x;
  int c = threadIdx.x;
  float s = 0.f, q = 0.f;
  for (int r = blockIdx.x; r < NPTS; r += gridDim.x) {
    float v = buf[(size_t)r * C + c];
    s += v; q += v * v;
  }
  atomicAdd(&ssum[c], s);
  atomicAdd(&ssq[c], q);
}

__global__ void finalize_kernel(const float* __restrict__ ssum, const float* __restrict__ ssq,
                                float* __restrict__ mu, float* __restrict__ inv) {
  int c = threadIdx.x;
  float m = ssum[c] / (float)NPTS;
  float v = ssq[c] / (float)NPTS - m * m;
  mu[c]  = m;
  inv[c] = rsqrtf(v + EPSV);
}

// ---------------- normalize + lrelu + row-mask -> bf16 (C = 128) ----------------
__global__ void ew_kernel(const float* __restrict__ in, const float* __restrict__ mu,
                          const float* __restrict__ inv, const float* __restrict__ rowmask,
                          bf16* __restrict__ outb) {
  int i = (blockIdx.x * blockDim.x + threadIdx.x) * 4;
  if (i >= NPTS * PCH) return;
  float4 v = *(const float4*)&in[i];
  int c = i & 127;
  int row = i >> 7;
  float mk = rowmask[row];
  float t0 = (v.x - mu[c + 0]) * inv[c + 0];
  float t1 = (v.y - mu[c + 1]) * inv[c + 1];
  float t2 = (v.z - mu[c + 2]) * inv[c + 2];
  float t3 = (v.w - mu[c + 3]) * inv[c + 3];
  t0 = (t0 >= 0.f ? t0 : NEGS * t0) * mk;
  t1 = (t1 >= 0.f ? t1 : NEGS * t1) * mk;
  t2 = (t2 >= 0.f ? t2 : NEGS * t2) * mk;
  t3 = (t3 >= 0.f ? t3 : NEGS * t3) * mk;
  bf16x4 o;
  o[0] = (bf16)t0; o[1] = (bf16)t1; o[2] = (bf16)t2; o[3] = (bf16)t3;
  *(bf16x4*)&outb[i] = o;
}

// ---------------- final: out = lrelu(inorm(out3) + x), in-place on d_out ------
__global__ void final_kernel(const float* __restrict__ x, const float* __restrict__ mu,
                             const float* __restrict__ inv, float* __restrict__ out) {
  int i = (blockIdx.x * blockDim.x + threadIdx.x) * 4;
  if (i >= NPTS * CIN) return;
  float4 v  = *(const float4*)&out[i];
  float4 xv = *(const float4*)&x[i];
  int c = i & 511;
  float t0 = (v.x - mu[c + 0]) * inv[c + 0] + xv.x;
  float t1 = (v.y - mu[c + 1]) * inv[c + 1] + xv.y;
  float t2 = (v.z - mu[c + 2]) * inv[c + 2] + xv.z;
  float t3 = (v.w - mu[c + 3]) * inv[c + 3] + xv.w;
  float4 o;
  o.x = t0 >= 0.f ? t0 : NEGS * t0;
  o.y = t1 >= 0.f ? t1 : NEGS * t1;
  o.z = t2 >= 0.f ? t2 : NEGS * t2;
  o.w = t3 >= 0.f ? t3 : NEGS * t3;
  *(float4*)&out[i] = o;
}

__global__ void maskout_kernel(const float* __restrict__ mask, const float* __restrict__ valid2,
                               float* __restrict__ outm) {
  int n = blockIdx.x * blockDim.x + threadIdx.x;
  if (n >= NPTS) return;
  outm[n] = fminf(valid2[n] + mask[n], 1.f);
}

// =================== GEMM kernels ===================
// MFMA 16x16x32 bf16. A frag: lane holds A[m=lane&15][k=quad*8+j].
// B frag: lane holds B^T[n=lane&15][k=quad*8+j]. C/D: col=lane&15, row=quad*4+reg.
#define LDA 136  // 128 + 8 bf16 pad (16B) to spread LDS banks

// GEMM1: out1[n][d] = (x[n][:] @ W1)[d] * valid[n];  x fp32 [N,512], w1t bf16 [128][512]
__global__ __launch_bounds__(256) void gemm1_kernel(
    const float* __restrict__ x, const bf16* __restrict__ w1t,
    const float* __restrict__ valid, float* __restrict__ out1) {
  __shared__ __align__(16) bf16 As[128 * LDA];
  __shared__ __align__(16) bf16 Bs[128 * LDA];
  int row0 = blockIdx.x * 128;
  int tid = threadIdx.x;
  int lane = tid & 63, wid = tid >> 6;
  int mq = (wid >> 1) * 64, nq = (wid & 1) * 64;
  int lr = lane & 15, lq = lane >> 4;
  f32x4 acc[4][4];
#pragma unroll
  for (int i = 0; i < 4; ++i)
#pragma unroll
    for (int j = 0; j < 4; ++j)
#pragma unroll
      for (int r = 0; r < 4; ++r) acc[i][j][r] = 0.f;

  for (int kc = 0; kc < 4; ++kc) {
#pragma unroll
    for (int j = 0; j < 8; ++j) {
      int e = (j * 256 + tid) * 8;
      int r = e >> 7, c = e & 127;
      float4 v0 = {0, 0, 0, 0}, v1 = {0, 0, 0, 0};
      if (row0 + r < NPTS) {
        const float* p = x + (size_t)(row0 + r) * CIN + kc * 128 + c;
        v0 = *(const float4*)p;
        v1 = *(const float4*)(p + 4);
      }
      bf16x8 w;
      w[0] = (bf16)v0.x; w[1] = (bf16)v0.y; w[2] = (bf16)v0.z; w[3] = (bf16)v0.w;
      w[4] = (bf16)v1.x; w[5] = (bf16)v1.y; w[6] = (bf16)v1.z; w[7] = (bf16)v1.w;
      *(bf16x8*)&As[r * LDA + c] = w;
    }
#pragma unroll
    for (int j = 0; j < 8; ++j) {
      int e = (j * 256 + tid) * 8;
      int r = e >> 7, c = e & 127;
      *(bf16x8*)&Bs[r * LDA + c] = *(const bf16x8*)&w1t[(size_t)r * CIN + kc * 128 + c];
    }
    __syncthreads();
#pragma unroll
    for (int c0 = 0; c0 < 128; c0 += 32) {
      bf16x8 af[4], bfg[4];
#pragma unroll
      for (int i = 0; i < 4; ++i) af[i]  = *(const bf16x8*)&As[(mq + i * 16 + lr) * LDA + c0 + lq * 8];
#pragma unroll
      for (int i = 0; i < 4; ++i) bfg[i] = *(const bf16x8*)&Bs[(nq + i * 16 + lr) * LDA + c0 + lq * 8];
#pragma unroll
      for (int i = 0; i < 4; ++i)
#pragma unroll
        for (int j = 0; j < 4; ++j)
          acc[i][j] = __builtin_amdgcn_mfma_f32_16x16x32_bf16(af[i], bfg[j], acc[i][j], 0, 0, 0);
    }
    __syncthreads();
  }
#pragma unroll
  for (int i = 0; i < 4; ++i) {
    int rbase = row0 + mq + i * 16 + lq * 4;
#pragma unroll
    for (int j = 0; j < 4; ++j) {
      int col = nq + j * 16 + lr;
#pragma unroll
      for (int r = 0; r < 4; ++r) {
        int row = rbase + r;
        if (row < NPTS) out1[(size_t)row * PCH + col] = acc[i][j][r] * valid[row];
      }
    }
  }
}

// GEMM2 (gather): out2[n][d] = ratio[n] * sum_{k,c} out1n[nbr[n][k]][c] * W2[k][c][d]
__global__ __launch_bounds__(256) void gemm2_kernel(
    const bf16* __restrict__ a, const bf16* __restrict__ w2t,
    const int* __restrict__ nbrT, const float* __restrict__ ratio,
    float* __restrict__ out2) {
  __shared__ __align__(16) bf16 As[128 * LDA];
  __shared__ __align__(16) bf16 Bs[128 * LDA];
  int row0 = blockIdx.x * 128;
  int tid = threadIdx.x;
  int lane = tid & 63, wid = tid >> 6;
  int mq = (wid >> 1) * 64, nq = (wid & 1) * 64;
  int lr = lane & 15, lq = lane >> 4;
  f32x4 acc[4][4];
#pragma unroll
  for (int i = 0; i < 4; ++i)
#pragma unroll
    for (int j = 0; j < 4; ++j)
#pragma unroll
      for (int r = 0; r < 4; ++r) acc[i][j][r] = 0.f;

  for (int k = 0; k < KNB; ++k) {
#pragma unroll
    for (int j = 0; j < 8; ++j) {
      int e = (j * 256 + tid) * 8;
      int r = e >> 7, c = e & 127;
      int row = row0 + r;
      bf16x8 v;
#pragma unroll
      for (int q = 0; q < 8; ++q) v[q] = (bf16)0.f;
      if (row < NPTS) {
        int src = nbrT[k * NPTS + row];
        v = *(const bf16x8*)&a[(size_t)src * PCH + c];
      }
      *(bf16x8*)&As[r * LDA + c] = v;
    }
#pragma unroll
    for (int j = 0; j < 8; ++j) {
      int e = (j * 256 + tid) * 8;
      int r = e >> 7, c = e & 127;
      *(bf16x8*)&Bs[r * LDA + c] = *(const bf16x8*)&w2t[(size_t)r * (KNB * PCH) + k * 128 + c];
    }
    __syncthreads();
#pragma unroll
    for (int c0 = 0; c0 < 128; c0 += 32) {
      bf16x8 af[4], bfg[4];
#pragma unroll
      for (int i = 0; i < 4; ++i) af[i]  = *(const bf16x8*)&As[(mq + i * 16 + lr) * LDA + c0 + lq * 8];
#pragma unroll
      for (int i = 0; i < 4; ++i) bfg[i] = *(const bf16x8*)&Bs[(nq + i * 16 + lr) * LDA + c0 + lq * 8];
#pragma unroll
      for (int i = 0; i < 4; ++i)
#pragma unroll
        for (int j = 0; j < 4; ++j)
          acc[i][j] = __builtin_amdgcn_mfma_f32_16x16x32_bf16(af[i], bfg[j], acc[i][j], 0, 0, 0);
    }
    __syncthreads();
  }
#pragma unroll
  for (int i = 0; i < 4; ++i) {
    int rbase = row0 + mq + i * 16 + lq * 4;
#pragma unroll
    for (int j = 0; j < 4; ++j) {
      int col = nq + j * 16 + lr;
#pragma unroll
      for (int r = 0; r < 4; ++r) {
        int row = rbase + r;
        if (row < NPTS) out2[(size_t)row * PCH + col] = acc[i][j][r] * ratio[row];
      }
    }
  }
}

// GEMM3: out3[n][d] = out2n[n][:] @ W3[:, d];  A bf16 [N,128], w3t bf16 [512][128]
__global__ __launch_bounds__(256) void gemm3_kernel(
    const bf16* __restrict__ a, const bf16* __restrict__ w3t, float* __restrict__ out3) {
  __shared__ __align__(16) bf16 As[128 * LDA];
  __shared__ __align__(16) bf16 Bs[128 * LDA];
  int row0 = blockIdx.x * 128;
  int ncol0 = blockIdx.y * 128;
  int tid = threadIdx.x;
  int lane = tid & 63, wid = tid >> 6;
  int mq = (wid >> 1) * 64, nq = (wid & 1) * 64;
  int lr = lane & 15, lq = lane >> 4;
  f32x4 acc[4][4];
#pragma unroll
  for (int i = 0; i < 4; ++i)
#pragma unroll
    for (int j = 0; j < 4; ++j)
#pragma unroll
      for (int r = 0; r < 4; ++r) acc[i][j][r] = 0.f;

#pragma unroll
  for (int j = 0; j < 8; ++j) {
    int e = (j * 256 + tid) * 8;
    int r = e >> 7, c = e & 127;
    int row = row0 + r;
    bf16x8 v;
#pragma unroll
    for (int q = 0; q < 8; ++q) v[q] = (bf16)0.f;
    if (row < NPTS) v = *(const bf16x8*)&a[(size_t)row * PCH + c];
    *(bf16x8*)&As[r * LDA + c] = v;
  }
#pragma unroll
  for (int j = 0; j < 8; ++j) {
    int e = (j * 256 + tid) * 8;
    int r = e >> 7, c = e & 127;
    *(bf16x8*)&Bs[r * LDA + c] = *(const bf16x8*)&w3t[(size_t)(ncol0 + r) * PCH + c];
  }
  __syncthreads();
#pragma unroll
  for (int c0 = 0; c0 < 128; c0 += 32) {
    bf16x8 af[4], bfg[4];
#pragma unroll
    for (int i = 0; i < 4; ++i) af[i]  = *(const bf16x8*)&As[(mq + i * 16 + lr) * LDA + c0 + lq * 8];
#pragma unroll
    for (int i = 0; i < 4; ++i) bfg[i] = *(const bf16x8*)&Bs[(nq + i * 16 + lr) * LDA + c0 + lq * 8];
#pragma unroll
    for (int i = 0; i < 4; ++i)
#pragma unroll
      for (int j = 0; j < 4; ++j)
        acc[i][j] = __builtin_amdgcn_mfma_f32_16x16x32_bf16(af[i], bfg[j], acc[i][j], 0, 0, 0);
  }
#pragma unroll
  for (int i = 0; i < 4; ++i) {
    int rbase = row0 + mq + i * 16 + lq * 4;
#pragma unroll
    for (int j = 0; j < 4; ++j) {
      int col = ncol0 + nq + j * 16 + lr;
#pragma unroll
      for (int r = 0; r < 4; ++r) {
        int row = rbase + r;
        if (row < NPTS) out3[(size_t)row * CIN + col] = acc[i][j][r];
      }
    }
  }
}

// =================== launch ===================
extern "C" void kernel_launch(void* const* d_in, const int* in_sizes, int n_in,
                              void* d_out, int out_size, void* d_ws, size_t ws_size,
                              hipStream_t stream) {
  const float* x    = (const float*)d_in[0];
  const float* mask = (const float*)d_in[1];
  const int*   nbr  = (const int*)d_in[2];
  const float* W1   = (const float*)d_in[3];
  const float* W2   = (const float*)d_in[4];
  const float* W3   = (const float*)d_in[5];
  float* out = (float*)d_out;
  char* ws = (char*)d_ws;

  auto al = [](size_t x_) { return (x_ + 255) & ~(size_t)255; };
  size_t off = 0;
  size_t OFF_OUT1  = off; off += al((size_t)NPTS * PCH * 4);
  size_t OFF_OUT2  = off; off += al((size_t)NPTS * PCH * 4);
  size_t OFF_OUT1N = off; off += al((size_t)NPTS * PCH * 2);
  size_t OFF_OUT2N = off; off += al((size_t)NPTS * PCH * 2);
  size_t OFF_W1T   = off; off += al((size_t)PCH * CIN * 2);
  size_t OFF_W2T   = off; off += al((size_t)PCH * KNB * PCH * 2);
  size_t OFF_W3T   = off; off += al((size_t)CIN * PCH * 2);
  size_t OFF_NBRT  = off; off += al((size_t)KNB * NPTS * 4);
  size_t OFF_VALID = off; off += al((size_t)NPTS * 4);
  size_t OFF_RATIO = off; off += al((size_t)NPTS * 4);
  size_t OFF_VAL2  = off; off += al((size_t)NPTS * 4);
  size_t OFF_SUMS  = off; off += al((size_t)(128 + 128 + 128 + 128 + 512 + 512) * 4);
  size_t OFF_PRMS  = off; off += al((size_t)(128 + 128 + 128 + 128 + 512 + 512) * 4);

  float* out1   = (float*)(ws + OFF_OUT1);
  float* out2   = (float*)(ws + OFF_OUT2);
  bf16*  out1n  = (bf16*)(ws + OFF_OUT1N);
  bf16*  out2n  = (bf16*)(ws + OFF_OUT2N);
  bf16*  w1t    = (bf16*)(ws + OFF_W1T);
  bf16*  w2t    = (bf16*)(ws + OFF_W2T);
  bf16*  w3t    = (bf16*)(ws + OFF_W3T);
  int*   nbrT   = (int*)(ws + OFF_NBRT);
  float* valid  = (float*)(ws + OFF_VALID);
  float* ratio  = (float*)(ws + OFF_RATIO);
  float* valid2 = (float*)(ws + OFF_VAL2);
  float* sums   = (float*)(ws + OFF_SUMS);
  float* s1sum = sums, *s1sq = sums + 128;
  float* s2sum = sums + 256, *s2sq = sums + 384;
  float* s3sum = sums + 512, *s3sq = sums + 1024;
  float* prms = (float*)(ws + OFF_PRMS);
  float* mu1 = prms, *inv1 = prms + 128;
  float* mu2 = prms + 256, *inv2 = prms + 384;
  float* mu3 = prms + 512, *inv3 = prms + 1024;

  hipMemsetAsync(sums, 0, 1536 * 4, stream);

  tcvt_kernel<<<(CIN * PCH + 255) / 256, 256, 0, stream>>>(W1, w1t, CIN, PCH);
  tcvt_kernel<<<(KNB * PCH * PCH + 255) / 256, 256, 0, stream>>>(W2, w2t, KNB * PCH, PCH);
  tcvt_kernel<<<(PCH * CIN + 255) / 256, 256, 0, stream>>>(W3, w3t, PCH, CIN);
  valid_kernel<<<(NPTS + 255) / 256, 256, 0, stream>>>(mask, valid);
  nbrT_kernel<<<(KNB * NPTS + 255) / 256, 256, 0, stream>>>(nbr, nbrT);
  msum_kernel<<<(NPTS + 255) / 256, 256, 0, stream>>>(nbr, valid, ratio, valid2);

  int mblocks = (NPTS + 127) / 128;  // 391
  gemm1_kernel<<<mblocks, 256, 0, stream>>>(x, w1t, valid, out1);
  stats_kernel<<<128, 128, 0, stream>>>(out1, s1sum, s1sq);
  finalize_kernel<<<1, 128, 0, stream>>>(s1sum, s1sq, mu1, inv1);
  ew_kernel<<<(NPTS * PCH / 4 + 255) / 256, 256, 0, stream>>>(out1, mu1, inv1, valid, out1n);

  gemm2_kernel<<<mblocks, 256, 0, stream>>>(out1n, w2t, nbrT, ratio, out2);
  stats_kernel<<<128, 128, 0, stream>>>(out2, s2sum, s2sq);
  finalize_kernel<<<1, 128, 0, stream>>>(s2sum, s2sq, mu2, inv2);
  ew_kernel<<<(NPTS * PCH / 4 + 255) / 256, 256, 0, stream>>>(out2, mu2, inv2, valid2, out2n);

  dim3 g3(mblocks, 4);
  gemm3_kernel<<<g3, 256, 0, stream>>>(out2n, w3t, out);
  stats_kernel<<<128, 512, 0, stream>>>(out, s3sum, s3sq);
  finalize_kernel<<<1, 512, 0, stream>>>(s3sum, s3sq, mu3, inv3);
  final_kernel<<<(NPTS * CIN / 4 + 255) / 256, 256, 0, stream>>>(x, mu3, inv3, out);
  maskout_kernel<<<(NPTS + 255) / 256, 256, 0, stream>>>(mask, valid2, out + (size_t)NPTS * CIN);
}

// Round 2
// 567.078 us; speedup vs baseline: 1.3872x; 1.3872x over previous
//
#include <hip/hip_runtime.h>
#include <hip/hip_bf16.h>

#define NPTS 50000
#define CIN  512
#define PCH  128
#define KNB  27
#define EPSV 1e-5f
#define NEGS 0.1f

typedef __bf16 bf16;
typedef __bf16 bf16x8 __attribute__((ext_vector_type(8)));
typedef __bf16 bf16x4 __attribute__((ext_vector_type(4)));
typedef float  f32x4  __attribute__((ext_vector_type(4)));

#define LDA 136  // 128 + 8 bf16 pad: row stride 272B -> 2-way b128 aliasing (free per m136)

// ---------------- generic weight transpose+cvt: dst[C][R] = src[R][C] ----
__global__ void tcvt_kernel(const float* __restrict__ src, bf16* __restrict__ dst,
                            int R, int Ccols) {
  int i = blockIdx.x * blockDim.x + threadIdx.x;
  if (i >= R * Ccols) return;
  int c = i / R, r = i - c * R;
  dst[i] = (bf16)src[(size_t)r * Ccols + c];
}

// ---------------- W2 [k][c][d] -> w2k [k][d][c] (bf16) ----------------
__global__ void tcvt_w2k_kernel(const float* __restrict__ src, bf16* __restrict__ dst) {
  int i = blockIdx.x * blockDim.x + threadIdx.x;
  if (i >= KNB * PCH * PCH) return;
  int k = i >> 14, rem = i & 16383;
  int d = rem >> 7, c = rem & 127;
  dst[i] = (bf16)src[(k << 14) + c * 128 + d];
}

// ---------------- prep: nbrT + coverage ratio + valid2 ----------------
__global__ void prep_kernel(const int* __restrict__ nbr, const float* __restrict__ mask,
                            int* __restrict__ nbrT, float* __restrict__ ratio,
                            float* __restrict__ valid2) {
  int n = blockIdx.x * blockDim.x + threadIdx.x;
  if (n >= NPTS) return;
  float s = 0.f;
#pragma unroll
  for (int k = 0; k < KNB; ++k) {
    int idx = nbr[n * KNB + k];
    nbrT[k * NPTS + n] = idx;
    s += (mask[idx] > 0.f) ? 1.f : 0.f;
  }
  ratio[n]  = s > 0.f ? 27.0f / s : 0.f;
  valid2[n] = s > 0.f ? 1.f : 0.f;
}

__global__ void finalize_kernel(const float* __restrict__ ssum, const float* __restrict__ ssq,
                                float* __restrict__ mu, float* __restrict__ inv) {
  int c = threadIdx.x;
  float m = ssum[c] / (float)NPTS;
  float v = ssq[c] / (float)NPTS - m * m;
  mu[c]  = m;
  inv[c] = rsqrtf(v + EPSV);
}

// ---------------- normalize + lrelu + row-mask -> bf16 (C = 128) ----------------
__global__ void ew_kernel(const float* __restrict__ in, const float* __restrict__ mu,
                          const float* __restrict__ inv, const float* __restrict__ rowmask,
                          bf16* __restrict__ outb) {
  int i = (blockIdx.x * blockDim.x + threadIdx.x) * 4;
  if (i >= NPTS * PCH) return;
  float4 v = *(const float4*)&in[i];
  int c = i & 127;
  int row = i >> 7;
  float mk = rowmask[row];
  float t0 = (v.x - mu[c + 0]) * inv[c + 0];
  float t1 = (v.y - mu[c + 1]) * inv[c + 1];
  float t2 = (v.z - mu[c + 2]) * inv[c + 2];
  float t3 = (v.w - mu[c + 3]) * inv[c + 3];
  t0 = (t0 >= 0.f ? t0 : NEGS * t0) * mk;
  t1 = (t1 >= 0.f ? t1 : NEGS * t1) * mk;
  t2 = (t2 >= 0.f ? t2 : NEGS * t2) * mk;
  t3 = (t3 >= 0.f ? t3 : NEGS * t3) * mk;
  bf16x4 o;
  o[0] = (bf16)t0; o[1] = (bf16)t1; o[2] = (bf16)t2; o[3] = (bf16)t3;
  *(bf16x4*)&outb[i] = o;
}

// ---------------- final: out = lrelu(inorm(out3n) + x), out3n bf16 ----------------
__global__ void final_kernel(const float* __restrict__ x, const bf16* __restrict__ out3n,
                             const float* __restrict__ mu, const float* __restrict__ inv,
                             float* __restrict__ out) {
  int i = (blockIdx.x * blockDim.x + threadIdx.x) * 8;
  if (i >= NPTS * CIN) return;
  bf16x8 v = *(const bf16x8*)&out3n[i];
  float4 x0 = *(const float4*)&x[i];
  float4 x1 = *(const float4*)&x[i + 4];
  int c = i & 511;
  float t[8];
  float xv[8] = {x0.x, x0.y, x0.z, x0.w, x1.x, x1.y, x1.z, x1.w};
#pragma unroll
  for (int q = 0; q < 8; ++q) {
    float u = ((float)v[q] - mu[c + q]) * inv[c + q] + xv[q];
    t[q] = u >= 0.f ? u : NEGS * u;
  }
  float4 o0 = {t[0], t[1], t[2], t[3]}, o1 = {t[4], t[5], t[6], t[7]};
  *(float4*)&out[i] = o0;
  *(float4*)&out[i + 4] = o1;
}

__global__ void maskout_kernel(const float* __restrict__ mask, const float* __restrict__ valid2,
                               float* __restrict__ outm) {
  int n = blockIdx.x * blockDim.x + threadIdx.x;
  if (n >= NPTS) return;
  outm[n] = fminf(valid2[n] + mask[n], 1.f);
}

// =================== GEMM kernels ===================
// MFMA 16x16x32 bf16. A frag: lane holds A[m=lane&15][k=(lane>>4)*8+j].
// B frag: lane holds B^T[n=lane&15][k=(lane>>4)*8+j]. C/D: col=lane&15, row=(lane>>4)*4+reg.
// B tiles are L2-resident -> loaded straight to registers (no LDS); As single buffer
// (34816 B) -> 4 blocks/CU. Per-channel stats fused into epilogue.

// GEMM1: out1[n][d] = (x[n][:] @ W1)[d] * (mask[n]>0)
__global__ __launch_bounds__(256) void gemm1_kernel(
    const float* __restrict__ x, const bf16* __restrict__ w1t,
    const float* __restrict__ mask, float* __restrict__ out1,
    float* __restrict__ ssum, float* __restrict__ ssq) {
  __shared__ __align__(16) bf16 As[128 * LDA];
  int row0 = blockIdx.x * 128;
  int tid = threadIdx.x;
  int lane = tid & 63, wid = tid >> 6;
  int mq = (wid >> 1) * 64, nq = (wid & 1) * 64;
  int lr = lane & 15, lq = lane >> 4;
  f32x4 acc[4][4];
#pragma unroll
  for (int i = 0; i < 4; ++i)
#pragma unroll
    for (int j = 0; j < 4; ++j)
#pragma unroll
      for (int r = 0; r < 4; ++r) acc[i][j][r] = 0.f;

  for (int kc = 0; kc < 4; ++kc) {
#pragma unroll
    for (int j = 0; j < 8; ++j) {
      int e = (j * 256 + tid) * 8;
      int r = e >> 7, c = e & 127;
      float4 v0 = {0, 0, 0, 0}, v1 = {0, 0, 0, 0};
      if (row0 + r < NPTS) {
        const float* p = x + (size_t)(row0 + r) * CIN + kc * 128 + c;
        v0 = *(const float4*)p;
        v1 = *(const float4*)(p + 4);
      }
      bf16x8 w;
      w[0] = (bf16)v0.x; w[1] = (bf16)v0.y; w[2] = (bf16)v0.z; w[3] = (bf16)v0.w;
      w[4] = (bf16)v1.x; w[5] = (bf16)v1.y; w[6] = (bf16)v1.z; w[7] = (bf16)v1.w;
      *(bf16x8*)&As[r * LDA + c] = w;
    }
    __syncthreads();
    const bf16* bp = w1t + (size_t)(nq + lr) * CIN + kc * 128 + lq * 8;
#pragma unroll
    for (int c0 = 0; c0 < 128; c0 += 32) {
      bf16x8 af[4], bfg[4];
#pragma unroll
      for (int i = 0; i < 4; ++i) af[i]  = *(const bf16x8*)&As[(mq + i * 16 + lr) * LDA + c0 + lq * 8];
#pragma unroll
      for (int i = 0; i < 4; ++i) bfg[i] = *(const bf16x8*)(bp + (size_t)i * 16 * CIN + c0);
#pragma unroll
      for (int i = 0; i < 4; ++i)
#pragma unroll
        for (int j = 0; j < 4; ++j)
          acc[i][j] = __builtin_amdgcn_mfma_f32_16x16x32_bf16(af[i], bfg[j], acc[i][j], 0, 0, 0);
    }
    __syncthreads();
  }
  // epilogue: scale by mask, store, fused channel stats
  float rs[4][4];
#pragma unroll
  for (int i = 0; i < 4; ++i)
#pragma unroll
    for (int r = 0; r < 4; ++r) {
      int row = row0 + mq + i * 16 + lq * 4 + r;
      rs[i][r] = (row < NPTS) ? (mask[row] > 0.f ? 1.f : 0.f) : 0.f;
    }
#pragma unroll
  for (int j = 0; j < 4; ++j) {
    int col = nq + j * 16 + lr;
    float s = 0.f, q = 0.f;
#pragma unroll
    for (int i = 0; i < 4; ++i) {
#pragma unroll
      for (int r = 0; r < 4; ++r) {
        int row = row0 + mq + i * 16 + lq * 4 + r;
        if (row < NPTS) {
          float v = acc[i][j][r] * rs[i][r];
          out1[(size_t)row * PCH + col] = v;
          s += v; q += v * v;
        }
      }
    }
    s += __shfl_xor(s, 16); s += __shfl_xor(s, 32);
    q += __shfl_xor(q, 16); q += __shfl_xor(q, 32);
    if (lq == 0) { atomicAdd(&ssum[col], s); atomicAdd(&ssq[col], q); }
  }
}

// GEMM2 (gather): out2[n][d] = ratio[n] * sum_{k,c} out1n[nbr[k][n]][c] * w2k[k][d][c]
__global__ __launch_bounds__(256) void gemm2_kernel(
    const bf16* __restrict__ a, const bf16* __restrict__ w2k,
    const int* __restrict__ nbrT, const float* __restrict__ ratio,
    float* __restrict__ out2, float* __restrict__ ssum, float* __restrict__ ssq) {
  __shared__ __align__(16) bf16 As[128 * LDA];
  int row0 = blockIdx.x * 128;
  int tid = threadIdx.x;
  int lane = tid & 63, wid = tid >> 6;
  int mq = (wid >> 1) * 64, nq = (wid & 1) * 64;
  int lr = lane & 15, lq = lane >> 4;
  f32x4 acc[4][4];
#pragma unroll
  for (int i = 0; i < 4; ++i)
#pragma unroll
    for (int j = 0; j < 4; ++j)
#pragma unroll
      for (int r = 0; r < 4; ++r) acc[i][j][r] = 0.f;

  for (int k = 0; k < KNB; ++k) {
#pragma unroll
    for (int j = 0; j < 8; ++j) {
      int e = (j * 256 + tid) * 8;
      int r = e >> 7, c = e & 127;
      int row = row0 + r;
      bf16x8 v;
#pragma unroll
      for (int q = 0; q < 8; ++q) v[q] = (bf16)0.f;
      if (row < NPTS) {
        int src = nbrT[k * NPTS + row];
        v = *(const bf16x8*)&a[(size_t)src * PCH + c];
      }
      *(bf16x8*)&As[r * LDA + c] = v;
    }
    __syncthreads();
    const bf16* bp = w2k + (size_t)k * PCH * PCH + (nq + lr) * PCH + lq * 8;
#pragma unroll
    for (int c0 = 0; c0 < 128; c0 += 32) {
      bf16x8 af[4], bfg[4];
#pragma unroll
      for (int i = 0; i < 4; ++i) af[i]  = *(const bf16x8*)&As[(mq + i * 16 + lr) * LDA + c0 + lq * 8];
#pragma unroll
      for (int i = 0; i < 4; ++i) bfg[i] = *(const bf16x8*)(bp + (size_t)i * 16 * PCH + c0);
#pragma unroll
      for (int i = 0; i < 4; ++i)
#pragma unroll
        for (int j = 0; j < 4; ++j)
          acc[i][j] = __builtin_amdgcn_mfma_f32_16x16x32_bf16(af[i], bfg[j], acc[i][j], 0, 0, 0);
    }
    __syncthreads();
  }
  float rs[4][4];
#pragma unroll
  for (int i = 0; i < 4; ++i)
#pragma unroll
    for (int r = 0; r < 4; ++r) {
      int row = row0 + mq + i * 16 + lq * 4 + r;
      rs[i][r] = (row < NPTS) ? ratio[row] : 0.f;
    }
#pragma unroll
  for (int j = 0; j < 4; ++j) {
    int col = nq + j * 16 + lr;
    float s = 0.f, q = 0.f;
#pragma unroll
    for (int i = 0; i < 4; ++i) {
#pragma unroll
      for (int r = 0; r < 4; ++r) {
        int row = row0 + mq + i * 16 + lq * 4 + r;
        if (row < NPTS) {
          float v = acc[i][j][r] * rs[i][r];
          out2[(size_t)row * PCH + col] = v;
          s += v; q += v * v;
        }
      }
    }
    s += __shfl_xor(s, 16); s += __shfl_xor(s, 32);
    q += __shfl_xor(q, 16); q += __shfl_xor(q, 32);
    if (lq == 0) { atomicAdd(&ssum[col], s); atomicAdd(&ssq[col], q); }
  }
}

// GEMM3: out3n[n][d] = (bf16)(out2n[n][:] @ W3[:, d]); fused stats (fp32)
__global__ __launch_bounds__(256) void gemm3_kernel(
    const bf16* __restrict__ a, const bf16* __restrict__ w3t, bf16* __restrict__ out3n,
    float* __restrict__ ssum, float* __restrict__ ssq) {
  __shared__ __align__(16) bf16 As[128 * LDA];
  int row0 = blockIdx.x * 128;
  int ncol0 = blockIdx.y * 128;
  int tid = threadIdx.x;
  int lane = tid & 63, wid = tid >> 6;
  int mq = (wid >> 1) * 64, nq = (wid & 1) * 64;
  int lr = lane & 15, lq = lane >> 4;
  f32x4 acc[4][4];
#pragma unroll
  for (int i = 0; i < 4; ++i)
#pragma unroll
    for (int j = 0; j < 4; ++j)
#pragma unroll
      for (int r = 0; r < 4; ++r) acc[i][j][r] = 0.f;

#pragma unroll
  for (int j = 0; j < 8; ++j) {
    int e = (j * 256 + tid) * 8;
    int r = e >> 7, c = e & 127;
    int row = row0 + r;
    bf16x8 v;
#pragma unroll
    for (int q = 0; q < 8; ++q) v[q] = (bf16)0.f;
    if (row < NPTS) v = *(const bf16x8*)&a[(size_t)row * PCH + c];
    *(bf16x8*)&As[r * LDA + c] = v;
  }
  __syncthreads();
  const bf16* bp = w3t + (size_t)(ncol0 + nq + lr) * PCH + lq * 8;
#pragma unroll
  for (int c0 = 0; c0 < 128; c0 += 32) {
    bf16x8 af[4], bfg[4];
#pragma unroll
    for (int i = 0; i < 4; ++i) af[i]  = *(const bf16x8*)&As[(mq + i * 16 + lr) * LDA + c0 + lq * 8];
#pragma unroll
    for (int i = 0; i < 4; ++i) bfg[i] = *(const bf16x8*)(bp + (size_t)i * 16 * PCH + c0);
#pragma unroll
    for (int i = 0; i < 4; ++i)
#pragma unroll
      for (int j = 0; j < 4; ++j)
        acc[i][j] = __builtin_amdgcn_mfma_f32_16x16x32_bf16(af[i], bfg[j], acc[i][j], 0, 0, 0);
  }
#pragma unroll
  for (int j = 0; j < 4; ++j) {
    int col = ncol0 + nq + j * 16 + lr;
    float s = 0.f, q = 0.f;
#pragma unroll
    for (int i = 0; i < 4; ++i) {
#pragma unroll
      for (int r = 0; r < 4; ++r) {
        int row = row0 + mq + i * 16 + lq * 4 + r;
        if (row < NPTS) {
          float v = acc[i][j][r];
          out3n[(size_t)row * CIN + col] = (bf16)v;
          s += v; q += v * v;
        }
      }
    }
    s += __shfl_xor(s, 16); s += __shfl_xor(s, 32);
    q += __shfl_xor(q, 16); q += __shfl_xor(q, 32);
    if (lq == 0) { atomicAdd(&ssum[col], s); atomicAdd(&ssq[col], q); }
  }
}

// =================== launch ===================
extern "C" void kernel_launch(void* const* d_in, const int* in_sizes, int n_in,
                              void* d_out, int out_size, void* d_ws, size_t ws_size,
                              hipStream_t stream) {
  const float* x    = (const float*)d_in[0];
  const float* mask = (const float*)d_in[1];
  const int*   nbr  = (const int*)d_in[2];
  const float* W1   = (const float*)d_in[3];
  const float* W2   = (const float*)d_in[4];
  const float* W3   = (const float*)d_in[5];
  float* out = (float*)d_out;
  char* ws = (char*)d_ws;

  auto al = [](size_t x_) { return (x_ + 255) & ~(size_t)255; };
  size_t off = 0;
  size_t OFF_OUT1  = off; off += al((size_t)NPTS * PCH * 4);   // fp32; also out3n lower half
  size_t OFF_OUT2  = off; off += al((size_t)NPTS * PCH * 4);   // fp32; also out3n upper half
  size_t OFF_OUT1N = off; off += al((size_t)NPTS * PCH * 2);
  size_t OFF_OUT2N = off; off += al((size_t)NPTS * PCH * 2);
  size_t OFF_W1T   = off; off += al((size_t)PCH * CIN * 2);
  size_t OFF_W2K   = off; off += al((size_t)KNB * PCH * PCH * 2);
  size_t OFF_W3T   = off; off += al((size_t)CIN * PCH * 2);
  size_t OFF_NBRT  = off; off += al((size_t)KNB * NPTS * 4);
  size_t OFF_RATIO = off; off += al((size_t)NPTS * 4);
  size_t OFF_VAL2  = off; off += al((size_t)NPTS * 4);
  size_t OFF_SUMS  = off; off += al((size_t)1536 * 4);
  size_t OFF_PRMS  = off; off += al((size_t)1536 * 4);

  float* out1   = (float*)(ws + OFF_OUT1);
  float* out2   = (float*)(ws + OFF_OUT2);
  bf16*  out3n  = (bf16*)(ws + OFF_OUT1);   // overlaps out1+out2 (both dead by gemm3)
  bf16*  out1n  = (bf16*)(ws + OFF_OUT1N);
  bf16*  out2n  = (bf16*)(ws + OFF_OUT2N);
  bf16*  w1t    = (bf16*)(ws + OFF_W1T);
  bf16*  w2k    = (bf16*)(ws + OFF_W2K);
  bf16*  w3t    = (bf16*)(ws + OFF_W3T);
  int*   nbrT   = (int*)(ws + OFF_NBRT);
  float* ratio  = (float*)(ws + OFF_RATIO);
  float* valid2 = (float*)(ws + OFF_VAL2);
  float* sums   = (float*)(ws + OFF_SUMS);
  float* s1sum = sums, *s1sq = sums + 128;
  float* s2sum = sums + 256, *s2sq = sums + 384;
  float* s3sum = sums + 512, *s3sq = sums + 1024;
  float* prms = (float*)(ws + OFF_PRMS);
  float* mu1 = prms, *inv1 = prms + 128;
  float* mu2 = prms + 256, *inv2 = prms + 384;
  float* mu3 = prms + 512, *inv3 = prms + 1024;

  hipMemsetAsync(sums, 0, 1536 * 4, stream);

  prep_kernel<<<(NPTS + 255) / 256, 256, 0, stream>>>(nbr, mask, nbrT, ratio, valid2);
  tcvt_kernel<<<(CIN * PCH + 255) / 256, 256, 0, stream>>>(W1, w1t, CIN, PCH);
  tcvt_w2k_kernel<<<(KNB * PCH * PCH + 255) / 256, 256, 0, stream>>>(W2, w2k);
  tcvt_kernel<<<(PCH * CIN + 255) / 256, 256, 0, stream>>>(W3, w3t, PCH, CIN);

  int mblocks = (NPTS + 127) / 128;  // 391
  gemm1_kernel<<<mblocks, 256, 0, stream>>>(x, w1t, mask, out1, s1sum, s1sq);
  finalize_kernel<<<1, 128, 0, stream>>>(s1sum, s1sq, mu1, inv1);
  ew_kernel<<<(NPTS * PCH / 4 + 255) / 256, 256, 0, stream>>>(out1, mu1, inv1, mask, out1n);

  gemm2_kernel<<<mblocks, 256, 0, stream>>>(out1n, w2k, nbrT, ratio, out2, s2sum, s2sq);
  finalize_kernel<<<1, 128, 0, stream>>>(s2sum, s2sq, mu2, inv2);
  ew_kernel<<<(NPTS * PCH / 4 + 255) / 256, 256, 0, stream>>>(out2, mu2, inv2, valid2, out2n);

  dim3 g3(mblocks, 4);
  gemm3_kernel<<<g3, 256, 0, stream>>>(out2n, w3t, out3n, s3sum, s3sq);
  finalize_kernel<<<1, 512, 0, stream>>>(s3sum, s3sq, mu3, inv3);
  final_kernel<<<(NPTS * CIN / 8 + 255) / 256, 256, 0, stream>>>(x, out3n, mu3, inv3, out);
  maskout_kernel<<<(NPTS + 255) / 256, 256, 0, stream>>>(mask, valid2, out + (size_t)NPTS * CIN);
}